// Round 4
// baseline (631.570 us; speedup 1.0000x reference)
//
#include <hip/hip_runtime.h>
#include <hip/hip_bf16.h>
#include <cstdint>
#include <cstddef>

// out[8192,4096] = x @ W^T + bias + 2*((x@A^T)@B^T)
// Fold: W' = W + 2*B@A (rank-16), then ONE bf16 MFMA GEMM: out = x @ W'^T + bias.
// R6: (a) revert X to precast bf16 (R5's fused-f32-X over-fetched 3x, L2 thrash);
//     (b) fold_w rewritten register-cached (A-chunk in VGPRs, 16x reuse,
//         compulsory traffic only) and merged with the cast (2 dispatches total);
//     (c) GEMM mfma_phase restructured into 4 interleaved clusters
//         {lgkm(2) -> issue 2 ds_reads -> 8 MFMA} so LDS reads overlap MFMA
//         (R3 counters showed perfect LDS+MFMA serial sum: 1129+1242~2382/phase).

#define IN_F   4096
#define OUT_F  4096
#define MROWS  8192   // 4*2048
#define RLORA  16
#define LORA_SCALE 2.0f

#define CAST_BLOCKS 16384   // 8 floats/thread: 16384*256*8 = 33,554,432 = MROWS*IN_F
#define FOLD_BLOCKS 512     // 16 i-chunks x 32 o-chunks

// GEMM geometry (R3-proven ring-4)
#define BM   256
#define BN   256
#define BKT  32
#define NT   (IN_F / BKT)   // 128 phases

typedef __bf16 bf16x8 __attribute__((ext_vector_type(8)));
typedef float  f32x4  __attribute__((ext_vector_type(4)));
typedef int    i32x4  __attribute__((ext_vector_type(4)));

__device__ __forceinline__ unsigned short f2bf_rne(float f) {
    union { float f; unsigned u; } v; v.f = f;
    unsigned u = v.u;
    return (unsigned short)((u + 0x7FFFu + ((u >> 16) & 1u)) >> 16);
}

__device__ __forceinline__ void gl_lds16(const unsigned short* g, unsigned short* l) {
    __builtin_amdgcn_global_load_lds(
        (const __attribute__((address_space(1))) unsigned int*)g,
        (__attribute__((address_space(3))) unsigned int*)l,
        16, 0, 0);
}

// ---- prep: [0,CAST) cast x f32->bf16 ; [CAST, CAST+FOLD) fold W' ----------
// Fold block = (i-chunk of 256 cols, o-chunk of 128 rows).
//   Stage A-chunk [16][256] f32 (16KB) + B-chunk [128][16] (8KB) in LDS.
//   Thread: holds A[r][its float4 col] in 64 VGPRs (read LDS once), then
//   loops 32 output rows: 1 coalesced W float4 + 4 LDS-broadcast B quads +
//   64 FMA + ushort4 store. All global traffic compulsory.

__global__ void prep_kernel(const float* __restrict__ x,
                            const float* __restrict__ W,
                            const float* __restrict__ A,
                            const float* __restrict__ B,
                            unsigned short* __restrict__ xb,
                            unsigned short* __restrict__ wb) {
    __shared__ float4 sA4[16 * 64];    // 16 KB  [r][c4]
    __shared__ float4 sB4[128 * 4];    // 8 KB   [o_local][r4]
    const int bid = blockIdx.x;
    const int tid = threadIdx.x;

    if (bid < CAST_BLOCKS) {
        const int i = bid * 256 + tid;            // 2 float4 per thread
        float4 v0 = ((const float4*)x)[i * 2];
        float4 v1 = ((const float4*)x)[i * 2 + 1];
        ushort4 o0, o1;
        o0.x = f2bf_rne(v0.x); o0.y = f2bf_rne(v0.y);
        o0.z = f2bf_rne(v0.z); o0.w = f2bf_rne(v0.w);
        o1.x = f2bf_rne(v1.x); o1.y = f2bf_rne(v1.y);
        o1.z = f2bf_rne(v1.z); o1.w = f2bf_rne(v1.w);
        ((ushort4*)xb)[i * 2]     = o0;
        ((ushort4*)xb)[i * 2 + 1] = o1;
        return;
    }

    const int fb = bid - CAST_BLOCKS;             // 0..511
    const int ic = fb & 15;                       // i-chunk (256 cols)
    const int oc = fb >> 4;                       // o-chunk (128 rows)
    const int c0 = ic * 256;
    const int o0 = oc * 128;

    for (int t = tid; t < 1024; t += 256) {       // stage A-chunk
        const int r = t >> 6, c = t & 63;
        sA4[t] = ((const float4*)(A + (size_t)r * IN_F + c0))[c];
    }
    for (int t = tid; t < 512; t += 256)          // stage B-chunk (contiguous)
        sB4[t] = ((const float4*)(B + (size_t)o0 * RLORA))[t];
    __syncthreads();

    const int c4 = tid & 63;                      // thread's float4 column
    const int og = tid >> 6;                      // 0..3
    float4 a[RLORA];
    #pragma unroll
    for (int r = 0; r < RLORA; ++r) a[r] = sA4[r * 64 + c4];

    for (int i = 0; i < 32; ++i) {
        const int ol = og * 32 + i;
        const int o  = o0 + ol;
        float4 w = ((const float4*)(W + (size_t)o * IN_F + c0))[c4];
        const float4 q0 = sB4[ol * 4 + 0];
        const float4 q1 = sB4[ol * 4 + 1];
        const float4 q2 = sB4[ol * 4 + 2];
        const float4 q3 = sB4[ol * 4 + 3];
        const float s[RLORA] = {q0.x,q0.y,q0.z,q0.w, q1.x,q1.y,q1.z,q1.w,
                                q2.x,q2.y,q2.z,q2.w, q3.x,q3.y,q3.z,q3.w};
        float ax = 0.f, ay = 0.f, az = 0.f, aw = 0.f;
        #pragma unroll
        for (int r = 0; r < RLORA; ++r) {
            ax += s[r] * a[r].x; ay += s[r] * a[r].y;
            az += s[r] * a[r].z; aw += s[r] * a[r].w;
        }
        w.x += LORA_SCALE * ax; w.y += LORA_SCALE * ay;
        w.z += LORA_SCALE * az; w.w += LORA_SCALE * aw;
        ushort4 ov;
        ov.x = f2bf_rne(w.x); ov.y = f2bf_rne(w.y);
        ov.z = f2bf_rne(w.z); ov.w = f2bf_rne(w.w);
        ((ushort4*)(wb + (size_t)o * IN_F + c0))[c4] = ov;
    }
}

// ---- GEMM: C[M,N] = Xb @ Wb^T + bias  (ring-4, interleaved clusters) -------
//
// LDS chunk swizzle (chunk = 16 B): LDS chunk q of a tile holds global chunk
// (row=q>>2, kc=(q&3)^((row>>1)&3)); gl_lds writes linear, source pre-swizzled.
// Pipeline: stage tile p+3 during phase p (ring-4, 32KB/slot); end-of-phase
// counted vmcnt confirms tile p+1; raw s_barrier. vmcnt never 0 in main loop.
// Phase schedule (NEW): reads b0-3,a0-3 burst; then 4 clusters of
// {lgkm(2) -> issue next 2 a-reads -> 8 MFMA} so the LDS pipe feeds during
// MFMA instead of bursting while MFMA idles (R3: serial 1129+1242 cyc/phase).

__device__ __forceinline__ void mfma_phase(unsigned bufb, unsigned aoff, unsigned boff,
                                           f32x4 (&acc)[8][4]) {
    const unsigned ab = bufb + aoff;
    const unsigned bb = bufb + boff;
    i32x4 aR[8]; i32x4 bR[4];
    asm volatile("ds_read_b128 %0, %1"             : "=v"(bR[0]) : "v"(bb));
    asm volatile("ds_read_b128 %0, %1 offset:1024" : "=v"(bR[1]) : "v"(bb));
    asm volatile("ds_read_b128 %0, %1 offset:2048" : "=v"(bR[2]) : "v"(bb));
    asm volatile("ds_read_b128 %0, %1 offset:3072" : "=v"(bR[3]) : "v"(bb));
    asm volatile("ds_read_b128 %0, %1"             : "=v"(aR[0]) : "v"(ab));
    asm volatile("ds_read_b128 %0, %1 offset:1024" : "=v"(aR[1]) : "v"(ab));
    asm volatile("ds_read_b128 %0, %1 offset:2048" : "=v"(aR[2]) : "v"(ab));
    asm volatile("ds_read_b128 %0, %1 offset:3072" : "=v"(aR[3]) : "v"(ab));

    // cluster 0: needs b0-3 + a0,a1 (first 6 of 8 outstanding)
    asm volatile("s_waitcnt lgkmcnt(2)" ::: "memory");
    __builtin_amdgcn_sched_barrier(0);
    asm volatile("ds_read_b128 %0, %1 offset:4096" : "=v"(aR[4]) : "v"(ab));
    asm volatile("ds_read_b128 %0, %1 offset:5120" : "=v"(aR[5]) : "v"(ab));
    __builtin_amdgcn_sched_barrier(0);
    __builtin_amdgcn_s_setprio(1);
    #pragma unroll
    for (int mi = 0; mi < 2; ++mi) {
        const bf16x8 a = __builtin_bit_cast(bf16x8, aR[mi]);
        #pragma unroll
        for (int nj = 0; nj < 4; ++nj)
            acc[mi][nj] = __builtin_amdgcn_mfma_f32_16x16x32_bf16(
                a, __builtin_bit_cast(bf16x8, bR[nj]), acc[mi][nj], 0, 0, 0);
    }
    // cluster 1: a2,a3  (outstanding after wait: a4,a5)
    asm volatile("s_waitcnt lgkmcnt(2)" ::: "memory");
    __builtin_amdgcn_sched_barrier(0);
    asm volatile("ds_read_b128 %0, %1 offset:6144" : "=v"(aR[6]) : "v"(ab));
    asm volatile("ds_read_b128 %0, %1 offset:7168" : "=v"(aR[7]) : "v"(ab));
    __builtin_amdgcn_sched_barrier(0);
    #pragma unroll
    for (int mi = 2; mi < 4; ++mi) {
        const bf16x8 a = __builtin_bit_cast(bf16x8, aR[mi]);
        #pragma unroll
        for (int nj = 0; nj < 4; ++nj)
            acc[mi][nj] = __builtin_amdgcn_mfma_f32_16x16x32_bf16(
                a, __builtin_bit_cast(bf16x8, bR[nj]), acc[mi][nj], 0, 0, 0);
    }
    // cluster 2: a4,a5  (outstanding after wait: a6,a7)
    asm volatile("s_waitcnt lgkmcnt(2)" ::: "memory");
    __builtin_amdgcn_sched_barrier(0);
    #pragma unroll
    for (int mi = 4; mi < 6; ++mi) {
        const bf16x8 a = __builtin_bit_cast(bf16x8, aR[mi]);
        #pragma unroll
        for (int nj = 0; nj < 4; ++nj)
            acc[mi][nj] = __builtin_amdgcn_mfma_f32_16x16x32_bf16(
                a, __builtin_bit_cast(bf16x8, bR[nj]), acc[mi][nj], 0, 0, 0);
    }
    // cluster 3: a6,a7
    asm volatile("s_waitcnt lgkmcnt(0)" ::: "memory");
    __builtin_amdgcn_sched_barrier(0);
    #pragma unroll
    for (int mi = 6; mi < 8; ++mi) {
        const bf16x8 a = __builtin_bit_cast(bf16x8, aR[mi]);
        #pragma unroll
        for (int nj = 0; nj < 4; ++nj)
            acc[mi][nj] = __builtin_amdgcn_mfma_f32_16x16x32_bf16(
                a, __builtin_bit_cast(bf16x8, bR[nj]), acc[mi][nj], 0, 0, 0);
    }
    __builtin_amdgcn_sched_barrier(0);
    __builtin_amdgcn_s_setprio(0);
}

__global__ __launch_bounds__(512, 2)
void gemm_bt_bias(const unsigned short* __restrict__ Xb,
                  const unsigned short* __restrict__ Wb,
                  const float* __restrict__ bias,
                  float* __restrict__ out) {
    __shared__ __align__(16) unsigned short smem[4 * 16384];  // 4 x (A 16KB + B 16KB)

    const int tid  = threadIdx.x;
    const int wave = tid >> 6;
    const int lane = tid & 63;
    const int quad = lane >> 4;
    const int r16  = lane & 15;
    const int wm   = wave >> 2;
    const int wn   = wave & 3;

    // XCD swizzle: XCD c owns N-tiles {2c,2c+1}; W panel 2x2MB L2-resident.
    const int bid = blockIdx.x;
    const int xcd = bid & 7;
    const int t   = bid >> 3;
    const int n0  = (xcd * 2 + (t & 1)) * BN;
    const int m0  = (t >> 1) * BM;

    const int q0  = wave * 128 + lane;
    const int q1  = q0 + 64;
    const int r0  = q0 >> 2, k0c = (q0 & 3) ^ ((r0 >> 1) & 3);
    const int r1  = q1 >> 2, k1c = (q1 & 3) ^ ((r1 >> 1) & 3);

    const unsigned short* gA0 = Xb + (size_t)(m0 + r0) * IN_F + k0c * 8;
    const unsigned short* gA1 = Xb + (size_t)(m0 + r1) * IN_F + k1c * 8;
    const unsigned short* gB0 = Wb + (size_t)(n0 + r0) * IN_F + k0c * 8;
    const unsigned short* gB1 = Wb + (size_t)(n0 + r1) * IN_F + k1c * 8;

    unsigned short* const lA0 = smem + wave * 1024;
    unsigned short* const lA1 = lA0 + 512;
    unsigned short* const lB0 = smem + 8192 + wave * 1024;
    unsigned short* const lB1 = lB0 + 512;

    const unsigned slot  = (unsigned)(quad ^ ((r16 >> 1) & 3));
    const unsigned aoff  = (unsigned)((wm * 128 + r16) * 64) + slot * 16;
    const unsigned boff  = 16384u + (unsigned)((wn * 64 + r16) * 64) + slot * 16;
    const unsigned sbase = (unsigned)(size_t)
        ((__attribute__((address_space(3))) unsigned short*)smem);

    f32x4 acc[8][4] = {};

#define STAGE(TILE) {                                                    \
    const unsigned off = (unsigned)(((TILE) & 3) << 14);                 \
    gl_lds16(gA0, lA0 + off); gl_lds16(gA1, lA1 + off);                  \
    gl_lds16(gB0, lB0 + off); gl_lds16(gB1, lB1 + off);                  \
    gA0 += BKT; gA1 += BKT; gB0 += BKT; gB1 += BKT; }

    // prologue: stage tiles 0,1,2
    STAGE(0) STAGE(1) STAGE(2)
    asm volatile("s_waitcnt vmcnt(8)" ::: "memory");   // tile 0 resident
    __builtin_amdgcn_s_barrier();

    for (int p = 0; p < NT; ++p) {
        if (p + 3 < NT) STAGE(p + 3)
        mfma_phase(sbase + ((unsigned)(p & 3) << 15), aoff, boff, acc);
        if (p + 3 < NT)       { asm volatile("s_waitcnt vmcnt(8)" ::: "memory"); }
        else if (p + 3 == NT) { asm volatile("s_waitcnt vmcnt(4)" ::: "memory"); }
        else                  { asm volatile("s_waitcnt vmcnt(0)" ::: "memory"); }
        __builtin_amdgcn_s_barrier();
    }
#undef STAGE

    // epilogue: C = acc + bias
    float bv[4];
    #pragma unroll
    for (int nj = 0; nj < 4; ++nj)
        bv[nj] = bias[n0 + wn * 64 + nj * 16 + r16];

    #pragma unroll
    for (int mi = 0; mi < 8; ++mi) {
        #pragma unroll
        for (int i = 0; i < 4; ++i) {
            const int mg = m0 + wm * 128 + mi * 16 + quad * 4 + i;
            float* orow = out + (size_t)mg * OUT_F + (n0 + wn * 64 + r16);
            #pragma unroll
            for (int nj = 0; nj < 4; ++nj)
                orow[nj * 16] = acc[mi][nj][i] + bv[nj];
        }
    }
}

// ---- launch ----------------------------------------------------------------

extern "C" void kernel_launch(void* const* d_in, const int* in_sizes, int n_in,
                              void* d_out, int out_size, void* d_ws, size_t ws_size,
                              hipStream_t stream) {
    const float* x    = (const float*)d_in[0];
    const float* W    = (const float*)d_in[1];
    const float* bias = (const float*)d_in[2];
    const float* A    = (const float*)d_in[3];
    const float* B    = (const float*)d_in[4];
    float* out = (float*)d_out;

    unsigned short* xb = (unsigned short*)d_ws;              // 64 MB bf16 x
    unsigned short* wb = xb + (size_t)MROWS * IN_F;          // 32 MB bf16 W'

    prep_kernel<<<CAST_BLOCKS + FOLD_BLOCKS, 256, 0, stream>>>(x, W, A, B, xb, wb);
    gemm_bt_bias<<<(MROWS / BM) * (OUT_F / BN), 512, 0, stream>>>(xb, wb, bias, out);
}

// Round 5
// 549.078 us; speedup vs baseline: 1.1502x; 1.1502x over previous
//
#include <hip/hip_runtime.h>
#include <hip/hip_bf16.h>
#include <cstdint>
#include <cstddef>

// out[8192,4096] = x @ W^T + bias + 2*((x@A^T)@B^T)
// Fold: W' = W + 2*B@A (rank-16), then ONE bf16 MFMA GEMM: out = x @ W'^T + bias.
// R7: (a) prep reverted to R1's merged prep (measured best: R6 rewrite was
//         +100us); (b) GEMM inner loop ported to the m201 8-phase schedule:
//         per 32-K slot, TWO phases of {ds_read frags -> stage 2 gl_lds ->
//         barrier -> lgkm(0) -> 16 MFMA -> barrier}, B-frags read once and
//         reused, counted vmcnt(8) once per slot. Ring-4 LDS + chunk swizzle
//         (0 bank conflicts) unchanged from R3/R6.

#define IN_F   4096
#define OUT_F  4096
#define MROWS  8192   // 4*2048
#define RLORA  16
#define LORA_SCALE 2.0f

#define CAST_BLOCKS 32768   // MROWS*IN_F / (4*256)
#define FOLD_BLOCKS 4096    // OUT_F

// GEMM geometry
#define BM   256
#define BN   256
#define BKT  32               // K per LDS slot
#define NT   (IN_F / BKT)     // 128 slots

typedef __bf16 bf16x8 __attribute__((ext_vector_type(8)));
typedef float  f32x4  __attribute__((ext_vector_type(4)));
typedef int    i32x4  __attribute__((ext_vector_type(4)));

__device__ __forceinline__ unsigned short f2bf_rne(float f) {
    union { float f; unsigned u; } v; v.f = f;
    unsigned u = v.u;
    return (unsigned short)((u + 0x7FFFu + ((u >> 16) & 1u)) >> 16);
}

__device__ __forceinline__ void gl_lds16(const unsigned short* g, unsigned short* l) {
    __builtin_amdgcn_global_load_lds(
        (const __attribute__((address_space(1))) unsigned int*)g,
        (__attribute__((address_space(3))) unsigned int*)l,
        16, 0, 0);
}

// ---- prep (R1 verbatim): [0,32768) cast x fp32->bf16; rest fold W' --------

__global__ void prep_kernel(const float* __restrict__ x,
                            const float* __restrict__ W,
                            const float* __restrict__ A,
                            const float* __restrict__ B,
                            unsigned short* __restrict__ xb,
                            unsigned short* __restrict__ wb) {
    __shared__ float sB[RLORA];
    const int bid = blockIdx.x;
    if (bid < CAST_BLOCKS) {
        int i = bid * blockDim.x + threadIdx.x;       // one float4 per thread
        float4 v = ((const float4*)x)[i];
        ushort4 o;
        o.x = f2bf_rne(v.x); o.y = f2bf_rne(v.y);
        o.z = f2bf_rne(v.z); o.w = f2bf_rne(v.w);
        ((ushort4*)xb)[i] = o;
    } else {
        const int o = bid - CAST_BLOCKS;              // output row
        if (threadIdx.x < RLORA) sB[threadIdx.x] = B[o * RLORA + threadIdx.x];
        __syncthreads();
        const float4* W4  = (const float4*)(W + (size_t)o * IN_F);
        ushort4*      Wp4 = (ushort4*)(wb + (size_t)o * IN_F);
        for (int i4 = threadIdx.x; i4 < IN_F / 4; i4 += blockDim.x) {
            float4 w = W4[i4];
            float ax = 0.f, ay = 0.f, az = 0.f, aw = 0.f;
            #pragma unroll
            for (int r = 0; r < RLORA; ++r) {
                float4 a = ((const float4*)(A + (size_t)r * IN_F))[i4];
                float s = sB[r];
                ax += s * a.x; ay += s * a.y; az += s * a.z; aw += s * a.w;
            }
            w.x += LORA_SCALE * ax; w.y += LORA_SCALE * ay;
            w.z += LORA_SCALE * az; w.w += LORA_SCALE * aw;
            ushort4 ov;
            ov.x = f2bf_rne(w.x); ov.y = f2bf_rne(w.y);
            ov.z = f2bf_rne(w.z); ov.w = f2bf_rne(w.w);
            Wp4[i4] = ov;
        }
    }
}

// ---- GEMM: C[M,N] = Xb @ Wb^T + bias  (ring-4, m201 8-phase schedule) ------
//
// LDS chunk swizzle (chunk = 16 B): LDS chunk q of a slot holds global chunk
// (row=q>>2, kc=(q&3)^((row>>1)&3)); gl_lds writes linear, source pre-swizzled.
// Ring-4 of 32-K slots (32 KB each). While computing slot p, slot p+3 stages.
// Per slot, TWO phases (m201 template):
//   phase A: read 4 B-frags + 4 A-frags (mi 0-3); stage 2 A-gl_lds(p+3);
//            BARRIER; lgkm(0); setprio1; 16 MFMA (mi 0-3); setprio0; BARRIER
//   phase B: read 4 A-frags (mi 4-7);             stage 2 B-gl_lds(p+3);
//            BARRIER; lgkm(0); setprio1; 16 MFMA (mi 4-7); setprio0;
//            vmcnt(8) [slot p+1 resident; p+2,p+3 = 8 loads in flight]; BARRIER
// vmcnt never drains to 0 in the main loop.

__global__ __launch_bounds__(512, 2)
void gemm_bt_bias(const unsigned short* __restrict__ Xb,
                  const unsigned short* __restrict__ Wb,
                  const float* __restrict__ bias,
                  float* __restrict__ out) {
    __shared__ __align__(16) unsigned short smem[4 * 16384];  // 4 x (A 16KB + B 16KB)

    const int tid  = threadIdx.x;
    const int wave = tid >> 6;
    const int lane = tid & 63;
    const int quad = lane >> 4;
    const int r16  = lane & 15;
    const int wm   = wave >> 2;     // 0..1 (M half: 128 rows)
    const int wn   = wave & 3;      // 0..3 (N quarter: 64 cols)

    // XCD swizzle: XCD c owns N-tiles {2c,2c+1}; W panel 4 MB = its whole L2.
    const int bid = blockIdx.x;
    const int xcd = bid & 7;
    const int t   = bid >> 3;
    const int n0  = (xcd * 2 + (t & 1)) * BN;
    const int m0  = (t >> 1) * BM;

    // staging geometry: thread owns LDS chunks q0, q1 of A and of B per slot
    const int q0  = wave * 128 + lane;
    const int q1  = q0 + 64;
    const int r0  = q0 >> 2, k0c = (q0 & 3) ^ ((r0 >> 1) & 3);
    const int r1  = q1 >> 2, k1c = (q1 & 3) ^ ((r1 >> 1) & 3);

    const unsigned short* gA0 = Xb + (size_t)(m0 + r0) * IN_F + k0c * 8;
    const unsigned short* gA1 = Xb + (size_t)(m0 + r1) * IN_F + k1c * 8;
    const unsigned short* gB0 = Wb + (size_t)(n0 + r0) * IN_F + k0c * 8;
    const unsigned short* gB1 = Wb + (size_t)(n0 + r1) * IN_F + k1c * 8;

    unsigned short* const lA0 = smem + wave * 1024;
    unsigned short* const lA1 = lA0 + 512;
    unsigned short* const lB0 = smem + 8192 + wave * 1024;
    unsigned short* const lB1 = lB0 + 512;

    // fragment read addresses (bytes, swizzled)
    const unsigned slot  = (unsigned)(quad ^ ((r16 >> 1) & 3));
    const unsigned aoff  = (unsigned)((wm * 128 + r16) * 64) + slot * 16;
    const unsigned boff  = 16384u + (unsigned)((wn * 64 + r16) * 64) + slot * 16;
    const unsigned sbase = (unsigned)(size_t)
        ((__attribute__((address_space(3))) unsigned short*)smem);

    f32x4 acc[8][4] = {};

#define STAGE_A(TILE) {                                                  \
    const unsigned off = (unsigned)(((TILE) & 3) << 14);                 \
    gl_lds16(gA0, lA0 + off); gl_lds16(gA1, lA1 + off);                  \
    gA0 += BKT; gA1 += BKT; }
#define STAGE_B(TILE) {                                                  \
    const unsigned off = (unsigned)(((TILE) & 3) << 14);                 \
    gl_lds16(gB0, lB0 + off); gl_lds16(gB1, lB1 + off);                  \
    gB0 += BKT; gB1 += BKT; }

    // prologue: stage slots 0,1,2 (12 loads); slot 0 resident at barrier
    STAGE_A(0) STAGE_B(0)
    STAGE_A(1) STAGE_B(1)
    STAGE_A(2) STAGE_B(2)
    asm volatile("s_waitcnt vmcnt(8)" ::: "memory");
    __builtin_amdgcn_s_barrier();

    for (int p = 0; p < NT; ++p) {
        const unsigned bufb = sbase + ((unsigned)(p & 3) << 15);
        const unsigned ab = bufb + aoff;
        const unsigned bb = bufb + boff;

        // ================= phase A =================
        i32x4 aR[4], bR[4], aS[4];
        asm volatile("ds_read_b128 %0, %1"             : "=v"(bR[0]) : "v"(bb));
        asm volatile("ds_read_b128 %0, %1 offset:1024" : "=v"(bR[1]) : "v"(bb));
        asm volatile("ds_read_b128 %0, %1 offset:2048" : "=v"(bR[2]) : "v"(bb));
        asm volatile("ds_read_b128 %0, %1 offset:3072" : "=v"(bR[3]) : "v"(bb));
        asm volatile("ds_read_b128 %0, %1"             : "=v"(aR[0]) : "v"(ab));
        asm volatile("ds_read_b128 %0, %1 offset:1024" : "=v"(aR[1]) : "v"(ab));
        asm volatile("ds_read_b128 %0, %1 offset:2048" : "=v"(aR[2]) : "v"(ab));
        asm volatile("ds_read_b128 %0, %1 offset:3072" : "=v"(aR[3]) : "v"(ab));
        if (p + 3 < NT) STAGE_A(p + 3)
        __builtin_amdgcn_s_barrier();
        asm volatile("s_waitcnt lgkmcnt(0)" ::: "memory");
        __builtin_amdgcn_sched_barrier(0);
        __builtin_amdgcn_s_setprio(1);
        #pragma unroll
        for (int mi = 0; mi < 4; ++mi) {
            const bf16x8 a = __builtin_bit_cast(bf16x8, aR[mi]);
            #pragma unroll
            for (int nj = 0; nj < 4; ++nj)
                acc[mi][nj] = __builtin_amdgcn_mfma_f32_16x16x32_bf16(
                    a, __builtin_bit_cast(bf16x8, bR[nj]), acc[mi][nj], 0, 0, 0);
        }
        __builtin_amdgcn_sched_barrier(0);
        __builtin_amdgcn_s_setprio(0);
        __builtin_amdgcn_s_barrier();

        // ================= phase B =================
        asm volatile("ds_read_b128 %0, %1 offset:4096" : "=v"(aS[0]) : "v"(ab));
        asm volatile("ds_read_b128 %0, %1 offset:5120" : "=v"(aS[1]) : "v"(ab));
        asm volatile("ds_read_b128 %0, %1 offset:6144" : "=v"(aS[2]) : "v"(ab));
        asm volatile("ds_read_b128 %0, %1 offset:7168" : "=v"(aS[3]) : "v"(ab));
        if (p + 3 < NT) STAGE_B(p + 3)
        __builtin_amdgcn_s_barrier();
        asm volatile("s_waitcnt lgkmcnt(0)" ::: "memory");
        __builtin_amdgcn_sched_barrier(0);
        __builtin_amdgcn_s_setprio(1);
        #pragma unroll
        for (int mi = 0; mi < 4; ++mi) {
            const bf16x8 a = __builtin_bit_cast(bf16x8, aS[mi]);
            #pragma unroll
            for (int nj = 0; nj < 4; ++nj)
                acc[mi + 4][nj] = __builtin_amdgcn_mfma_f32_16x16x32_bf16(
                    a, __builtin_bit_cast(bf16x8, bR[nj]), acc[mi + 4][nj], 0, 0, 0);
        }
        __builtin_amdgcn_sched_barrier(0);
        __builtin_amdgcn_s_setprio(0);
        // slot p+1 residency (in-order retirement; p+2,p+3 = 8 loads stay out)
        if (p + 3 < NT)       { asm volatile("s_waitcnt vmcnt(8)" ::: "memory"); }
        else if (p + 3 == NT) { asm volatile("s_waitcnt vmcnt(4)" ::: "memory"); }
        else                  { asm volatile("s_waitcnt vmcnt(0)" ::: "memory"); }
        __builtin_amdgcn_s_barrier();
    }
#undef STAGE_A
#undef STAGE_B

    // epilogue: C = acc + bias
    float bv[4];
    #pragma unroll
    for (int nj = 0; nj < 4; ++nj)
        bv[nj] = bias[n0 + wn * 64 + nj * 16 + r16];

    #pragma unroll
    for (int mi = 0; mi < 8; ++mi) {
        #pragma unroll
        for (int i = 0; i < 4; ++i) {
            const int mg = m0 + wm * 128 + mi * 16 + quad * 4 + i;
            float* orow = out + (size_t)mg * OUT_F + (n0 + wn * 64 + r16);
            #pragma unroll
            for (int nj = 0; nj < 4; ++nj)
                orow[nj * 16] = acc[mi][nj][i] + bv[nj];
        }
    }
}

// ---- launch ----------------------------------------------------------------

extern "C" void kernel_launch(void* const* d_in, const int* in_sizes, int n_in,
                              void* d_out, int out_size, void* d_ws, size_t ws_size,
                              hipStream_t stream) {
    const float* x    = (const float*)d_in[0];
    const float* W    = (const float*)d_in[1];
    const float* bias = (const float*)d_in[2];
    const float* A    = (const float*)d_in[3];
    const float* B    = (const float*)d_in[4];
    float* out = (float*)d_out;

    unsigned short* xb = (unsigned short*)d_ws;              // 64 MB bf16 x
    unsigned short* wb = xb + (size_t)MROWS * IN_F;          // 32 MB bf16 W'

    prep_kernel<<<CAST_BLOCKS + FOLD_BLOCKS, 256, 0, stream>>>(x, W, A, B, xb, wb);
    gemm_bt_bias<<<(MROWS / BM) * (OUT_F / BN), 512, 0, stream>>>(xb, wb, bias, out);
}

// Round 6
// 531.181 us; speedup vs baseline: 1.1890x; 1.0337x over previous
//
#include <hip/hip_runtime.h>
#include <hip/hip_bf16.h>
#include <cstdint>
#include <cstddef>

// out[8192,4096] = x @ W^T + bias + 2*((x@A^T)@B^T)
// Fold: W' = W + 2*B@A (rank-16), then ONE bf16 MFMA GEMM: out = x @ W'^T + bias.
// R8: cross-slot FRAGMENT double-buffering. R3/R6/R7 all serialized LDS-read
//     service against MFMA (each wave lgkm(0)-drained its own reads in-phase;
//     lockstep issue => all waves wait out the full ~1100cy LDS service, THEN
//     MFMA => 2475 cyc/slot = serial sum, MfmaUtil ~50%). Now slot p's MFMA
//     consumes regs read during p-1, while p+1's {B, A-lo} reads are issued
//     (ring-4: p+1 resident, vmcnt(4) at slot end confirms 2 slots ahead).
//     A-hi read at slot top, covered by cluster-1 via lgkm(8). 1 barrier/slot.

#define IN_F   4096
#define OUT_F  4096
#define MROWS  8192   // 4*2048
#define RLORA  16
#define LORA_SCALE 2.0f

#define CAST_BLOCKS 32768   // MROWS*IN_F / (4*256)
#define FOLD_BLOCKS 4096    // OUT_F

// GEMM geometry
#define BM   256
#define BN   256
#define BKT  32               // K per LDS slot
#define NT   (IN_F / BKT)     // 128 slots

typedef __bf16 bf16x8 __attribute__((ext_vector_type(8)));
typedef float  f32x4  __attribute__((ext_vector_type(4)));
typedef int    i32x4  __attribute__((ext_vector_type(4)));

__device__ __forceinline__ unsigned short f2bf_rne(float f) {
    union { float f; unsigned u; } v; v.f = f;
    unsigned u = v.u;
    return (unsigned short)((u + 0x7FFFu + ((u >> 16) & 1u)) >> 16);
}

__device__ __forceinline__ void gl_lds16(const unsigned short* g, unsigned short* l) {
    __builtin_amdgcn_global_load_lds(
        (const __attribute__((address_space(1))) unsigned int*)g,
        (__attribute__((address_space(3))) unsigned int*)l,
        16, 0, 0);
}

// ---- prep (R1 verbatim): [0,32768) cast x fp32->bf16; rest fold W' --------

__global__ void prep_kernel(const float* __restrict__ x,
                            const float* __restrict__ W,
                            const float* __restrict__ A,
                            const float* __restrict__ B,
                            unsigned short* __restrict__ xb,
                            unsigned short* __restrict__ wb) {
    __shared__ float sB[RLORA];
    const int bid = blockIdx.x;
    if (bid < CAST_BLOCKS) {
        int i = bid * blockDim.x + threadIdx.x;       // one float4 per thread
        float4 v = ((const float4*)x)[i];
        ushort4 o;
        o.x = f2bf_rne(v.x); o.y = f2bf_rne(v.y);
        o.z = f2bf_rne(v.z); o.w = f2bf_rne(v.w);
        ((ushort4*)xb)[i] = o;
    } else {
        const int o = bid - CAST_BLOCKS;              // output row
        if (threadIdx.x < RLORA) sB[threadIdx.x] = B[o * RLORA + threadIdx.x];
        __syncthreads();
        const float4* W4  = (const float4*)(W + (size_t)o * IN_F);
        ushort4*      Wp4 = (ushort4*)(wb + (size_t)o * IN_F);
        for (int i4 = threadIdx.x; i4 < IN_F / 4; i4 += blockDim.x) {
            float4 w = W4[i4];
            float ax = 0.f, ay = 0.f, az = 0.f, aw = 0.f;
            #pragma unroll
            for (int r = 0; r < RLORA; ++r) {
                float4 a = ((const float4*)(A + (size_t)r * IN_F))[i4];
                float s = sB[r];
                ax += s * a.x; ay += s * a.y; az += s * a.z; aw += s * a.w;
            }
            w.x += LORA_SCALE * ax; w.y += LORA_SCALE * ay;
            w.z += LORA_SCALE * az; w.w += LORA_SCALE * aw;
            ushort4 ov;
            ov.x = f2bf_rne(w.x); ov.y = f2bf_rne(w.y);
            ov.z = f2bf_rne(w.z); ov.w = f2bf_rne(w.w);
            Wp4[i4] = ov;
        }
    }
}

// ---- GEMM: C[M,N] = Xb @ Wb^T + bias  (ring-4, frag-double-buffered) -------
//
// LDS chunk swizzle (chunk = 16 B): LDS chunk q of a slot holds global chunk
// (row=q>>2, kc=(q&3)^((row>>1)&3)); gl_lds writes linear, source pre-swizzled.
// Residency: stage slot t during slot t-3; vmcnt(4) at end of slot s retires
// stages of s+1 AND s+2 (12 outstanding -> 4), so reads of s+2 issued during
// slot s+1 are safe. Register schedule per slot s (set X = s&1 ? O : E):
//   RD_HI: a_s[4..7] (4 ds_read, slot s buf)
//   RD_LO(next): b_{s+1}[0..3], a_{s+1}[0..3] (8 ds_read, slot s+1 buf)
//   STAGE(s+3); [1 sched_barrier]
//   cluster1: 16 MFMA on a_s[0..3] (ready: waited at end of slot s-1)
//   lgkm(8): a_s[4..7] done (oldest 4 of 12; LDS served them under cluster1)
//   cluster2: 16 MFMA on a_s[4..7]
//   lgkm(0): next-slot prefetch done; vmcnt(4|0); s_barrier   (1 barrier/slot)

__global__ __launch_bounds__(512, 2)
void gemm_bt_bias(const unsigned short* __restrict__ Xb,
                  const unsigned short* __restrict__ Wb,
                  const float* __restrict__ bias,
                  float* __restrict__ out) {
    __shared__ __align__(16) unsigned short smem[4 * 16384];  // 4 x (A 16KB + B 16KB)

    const int tid  = threadIdx.x;
    const int wave = tid >> 6;
    const int lane = tid & 63;
    const int quad = lane >> 4;
    const int r16  = lane & 15;
    const int wm   = wave >> 2;     // 0..1 (M half: 128 rows)
    const int wn   = wave & 3;      // 0..3 (N quarter: 64 cols)

    // XCD swizzle: XCD c owns N-tiles {2c,2c+1}; W panel 4 MB = its whole L2.
    const int bid = blockIdx.x;
    const int xcd = bid & 7;
    const int t   = bid >> 3;
    const int n0  = (xcd * 2 + (t & 1)) * BN;
    const int m0  = (t >> 1) * BM;

    // staging geometry: thread owns LDS chunks q0, q1 of A and of B per slot
    const int q0  = wave * 128 + lane;
    const int q1  = q0 + 64;
    const int r0  = q0 >> 2, k0c = (q0 & 3) ^ ((r0 >> 1) & 3);
    const int r1  = q1 >> 2, k1c = (q1 & 3) ^ ((r1 >> 1) & 3);

    const unsigned short* gA0 = Xb + (size_t)(m0 + r0) * IN_F + k0c * 8;
    const unsigned short* gA1 = Xb + (size_t)(m0 + r1) * IN_F + k1c * 8;
    const unsigned short* gB0 = Wb + (size_t)(n0 + r0) * IN_F + k0c * 8;
    const unsigned short* gB1 = Wb + (size_t)(n0 + r1) * IN_F + k1c * 8;

    unsigned short* const lA0 = smem + wave * 1024;
    unsigned short* const lA1 = lA0 + 512;
    unsigned short* const lB0 = smem + 8192 + wave * 1024;
    unsigned short* const lB1 = lB0 + 512;

    // fragment read addresses (bytes, swizzled)
    const unsigned slot  = (unsigned)(quad ^ ((r16 >> 1) & 3));
    const unsigned aoff  = (unsigned)((wm * 128 + r16) * 64) + slot * 16;
    const unsigned boff  = 16384u + (unsigned)((wn * 64 + r16) * 64) + slot * 16;
    const unsigned sbase = (unsigned)(size_t)
        ((__attribute__((address_space(3))) unsigned short*)smem);

    f32x4 acc[8][4] = {};
    i32x4 aE[8], bE[4], aO[8], bO[4];

#define STAGE(TILE) {                                                    \
    const unsigned off = (unsigned)(((TILE) & 3) << 14);                 \
    gl_lds16(gA0, lA0 + off); gl_lds16(gA1, lA1 + off);                  \
    gl_lds16(gB0, lB0 + off); gl_lds16(gB1, lB1 + off);                  \
    gA0 += BKT; gA1 += BKT; gB0 += BKT; gB1 += BKT; }

#define RD_LO(AV, BV, S) {                                               \
    const unsigned bufb_ = sbase + ((unsigned)((S) & 3) << 15);          \
    const unsigned ab_ = bufb_ + aoff, bb_ = bufb_ + boff;               \
    asm volatile("ds_read_b128 %0, %1"             : "=v"(BV[0]) : "v"(bb_)); \
    asm volatile("ds_read_b128 %0, %1 offset:1024" : "=v"(BV[1]) : "v"(bb_)); \
    asm volatile("ds_read_b128 %0, %1 offset:2048" : "=v"(BV[2]) : "v"(bb_)); \
    asm volatile("ds_read_b128 %0, %1 offset:3072" : "=v"(BV[3]) : "v"(bb_)); \
    asm volatile("ds_read_b128 %0, %1"             : "=v"(AV[0]) : "v"(ab_)); \
    asm volatile("ds_read_b128 %0, %1 offset:1024" : "=v"(AV[1]) : "v"(ab_)); \
    asm volatile("ds_read_b128 %0, %1 offset:2048" : "=v"(AV[2]) : "v"(ab_)); \
    asm volatile("ds_read_b128 %0, %1 offset:3072" : "=v"(AV[3]) : "v"(ab_)); }

#define RD_HI(AV, S) {                                                   \
    const unsigned bufb_ = sbase + ((unsigned)((S) & 3) << 15);          \
    const unsigned ab_ = bufb_ + aoff;                                   \
    asm volatile("ds_read_b128 %0, %1 offset:4096" : "=v"(AV[4]) : "v"(ab_)); \
    asm volatile("ds_read_b128 %0, %1 offset:5120" : "=v"(AV[5]) : "v"(ab_)); \
    asm volatile("ds_read_b128 %0, %1 offset:6144" : "=v"(AV[6]) : "v"(ab_)); \
    asm volatile("ds_read_b128 %0, %1 offset:7168" : "=v"(AV[7]) : "v"(ab_)); }

#define CLUSTER(AV, BV, MLO, MHI) {                                      \
    _Pragma("unroll")                                                    \
    for (int mi = MLO; mi < MHI; ++mi) {                                 \
        const bf16x8 a_ = __builtin_bit_cast(bf16x8, AV[mi]);            \
        _Pragma("unroll")                                                \
        for (int nj = 0; nj < 4; ++nj)                                   \
            acc[mi][nj] = __builtin_amdgcn_mfma_f32_16x16x32_bf16(       \
                a_, __builtin_bit_cast(bf16x8, BV[nj]), acc[mi][nj], 0, 0, 0); \
    } }

    // ---- prologue ----------------------------------------------------------
    STAGE(0) STAGE(1) STAGE(2)
    asm volatile("s_waitcnt vmcnt(4)" ::: "memory");   // slots 0 AND 1 resident
    __builtin_amdgcn_s_barrier();
    RD_LO(aE, bE, 0)
    asm volatile("s_waitcnt lgkmcnt(0)" ::: "memory");
    __builtin_amdgcn_sched_barrier(0);

    // ---- main loop: pairs of slots (0..125) --------------------------------
    for (int p = 0; p < NT - 2; p += 2) {
        // ---- even slot s = p (set E), prefetch O for s+1 ----
        RD_HI(aE, p)
        RD_LO(aO, bO, p + 1)
        STAGE(p + 3)                        // p+3 <= 127 in loop
        __builtin_amdgcn_sched_barrier(0);
        __builtin_amdgcn_s_setprio(1);
        CLUSTER(aE, bE, 0, 4)
        asm volatile("s_waitcnt lgkmcnt(8)" ::: "memory");   // aE[4..7] done
        __builtin_amdgcn_sched_barrier(0);
        CLUSTER(aE, bE, 4, 8)
        __builtin_amdgcn_s_setprio(0);
        __builtin_amdgcn_sched_barrier(0);
        asm volatile("s_waitcnt lgkmcnt(0)" ::: "memory");   // O prefetch done
        __builtin_amdgcn_sched_barrier(0);
        asm volatile("s_waitcnt vmcnt(4)" ::: "memory");     // p+1,p+2 resident
        __builtin_amdgcn_s_barrier();

        // ---- odd slot s = p+1 (set O), prefetch E for s+2 ----
        RD_HI(aO, p + 1)
        RD_LO(aE, bE, p + 2)
        if (p + 4 < NT) STAGE(p + 4)
        __builtin_amdgcn_sched_barrier(0);
        __builtin_amdgcn_s_setprio(1);
        CLUSTER(aO, bO, 0, 4)
        asm volatile("s_waitcnt lgkmcnt(8)" ::: "memory");   // aO[4..7] done
        __builtin_amdgcn_sched_barrier(0);
        CLUSTER(aO, bO, 4, 8)
        __builtin_amdgcn_s_setprio(0);
        __builtin_amdgcn_sched_barrier(0);
        asm volatile("s_waitcnt lgkmcnt(0)" ::: "memory");   // E prefetch done
        __builtin_amdgcn_sched_barrier(0);
        if (p + 4 < NT) { asm volatile("s_waitcnt vmcnt(4)" ::: "memory"); }
        else            { asm volatile("s_waitcnt vmcnt(0)" ::: "memory"); }
        __builtin_amdgcn_s_barrier();
    }

    // ---- peeled slot 126 (set E), prefetch O for 127; no stage -------------
    RD_HI(aE, NT - 2)
    RD_LO(aO, bO, NT - 1)
    __builtin_amdgcn_sched_barrier(0);
    __builtin_amdgcn_s_setprio(1);
    CLUSTER(aE, bE, 0, 4)
    asm volatile("s_waitcnt lgkmcnt(8)" ::: "memory");
    __builtin_amdgcn_sched_barrier(0);
    CLUSTER(aE, bE, 4, 8)
    __builtin_amdgcn_s_setprio(0);
    __builtin_amdgcn_sched_barrier(0);
    asm volatile("s_waitcnt lgkmcnt(0)" ::: "memory");
    __builtin_amdgcn_sched_barrier(0);
    asm volatile("s_waitcnt vmcnt(0)" ::: "memory");
    __builtin_amdgcn_s_barrier();

    // ---- peeled slot 127 (set O); no prefetch ------------------------------
    RD_HI(aO, NT - 1)
    __builtin_amdgcn_sched_barrier(0);
    __builtin_amdgcn_s_setprio(1);
    CLUSTER(aO, bO, 0, 4)
    asm volatile("s_waitcnt lgkmcnt(0)" ::: "memory");   // only 4 outstanding
    __builtin_amdgcn_sched_barrier(0);
    CLUSTER(aO, bO, 4, 8)
    __builtin_amdgcn_s_setprio(0);

#undef STAGE
#undef RD_LO
#undef RD_HI
#undef CLUSTER

    // ---- epilogue: C = acc + bias ------------------------------------------
    float bv[4];
    #pragma unroll
    for (int nj = 0; nj < 4; ++nj)
        bv[nj] = bias[n0 + wn * 64 + nj * 16 + r16];

    #pragma unroll
    for (int mi = 0; mi < 8; ++mi) {
        #pragma unroll
        for (int i = 0; i < 4; ++i) {
            const int mg = m0 + wm * 128 + mi * 16 + quad * 4 + i;
            float* orow = out + (size_t)mg * OUT_F + (n0 + wn * 64 + r16);
            #pragma unroll
            for (int nj = 0; nj < 4; ++nj)
                orow[nj * 16] = acc[mi][nj][i] + bv[nj];
        }
    }
}

// ---- launch ----------------------------------------------------------------

extern "C" void kernel_launch(void* const* d_in, const int* in_sizes, int n_in,
                              void* d_out, int out_size, void* d_ws, size_t ws_size,
                              hipStream_t stream) {
    const float* x    = (const float*)d_in[0];
    const float* W    = (const float*)d_in[1];
    const float* bias = (const float*)d_in[2];
    const float* A    = (const float*)d_in[3];
    const float* B    = (const float*)d_in[4];
    float* out = (float*)d_out;

    unsigned short* xb = (unsigned short*)d_ws;              // 64 MB bf16 x
    unsigned short* wb = xb + (size_t)MROWS * IN_F;          // 32 MB bf16 W'

    prep_kernel<<<CAST_BLOCKS + FOLD_BLOCKS, 256, 0, stream>>>(x, W, A, B, xb, wb);
    gemm_bt_bias<<<(MROWS / BM) * (OUT_F / BN), 512, 0, stream>>>(xb, wb, bias, out);
}